// Round 6
// baseline (342.157 us; speedup 1.0000x reference)
//
#include <hip/hip_runtime.h>

// NestedMoEModel: B=32768, D=256, H=256, G=8, E=8.
// softmax row-sum == 1 => gate branch drops; sum_e is linear =>
// single GEMM  out[32768,2048] = x @ (sum_e W_exp)^T + sum_e b_exp.
// R8: byte-exact R0 (the 334 µs optimum — every structural variant R1-R5
// regressed or was neutral). ONE change: C-epilogue stores are NONTEMPORAL
// (nt bit -> bypass L2). C is a 268 MB write-once stream 8x aggregate L2;
// regular stores write-allocate and evict the A-panel/B lines that are
// re-read 16x/256x by neighboring tiles.

typedef unsigned short u16;
typedef __bf16 bf16x8 __attribute__((ext_vector_type(8)));
typedef float f32x4 __attribute__((ext_vector_type(4)));

#define MB 32768   // batch (GEMM M)
#define NN 2048    // G*H   (GEMM N)
#define KK 256     // D     (GEMM K)
#define BK 64

__device__ __forceinline__ u16 f2bf(float f) {
    unsigned u = __builtin_bit_cast(unsigned, f);
    u += 0x7FFFu + ((u >> 16) & 1u);
    return (u16)(u >> 16);
}

__device__ __forceinline__ void gld16(const void* g, void* l) {
    // async global->LDS, 16B/lane; LDS dest must be wave-uniform base + lane*16
    __builtin_amdgcn_global_load_lds((const __attribute__((address_space(1))) void*)g,
                                     (__attribute__((address_space(3))) void*)l,
                                     16, 0, 0);
}

// ---------------- prep: Wsum/bsum fold + x fp32->bf16 (R0-exact) ----------------
__global__ __launch_bounds__(256) void prep_kernel(
    const float* __restrict__ x, const float* __restrict__ Wexp,
    const float* __restrict__ bexp, u16* __restrict__ xb,
    u16* __restrict__ Ws, float* __restrict__ bs)
{
    const int blk = blockIdx.x;
    const int t = threadIdx.x;
    if (blk < 512) {
        const int tid = blk * 256 + t;        // 0..131071
        const int n = tid >> 6;               // 0..2047
        const int i = (tid & 63) << 2;        // 0..252
        const int g = n >> 8, h = n & 255;
        const float* base = Wexp + ((size_t)(g * 8) * 256 + h) * 256 + i;
        float s0 = 0.f, s1 = 0.f, s2 = 0.f, s3 = 0.f;
#pragma unroll
        for (int e = 0; e < 8; ++e) {
            const float4 v = *(const float4*)(base + (size_t)e * 65536);
            s0 += v.x; s1 += v.y; s2 += v.z; s3 += v.w;
        }
        ushort4 o;
        o.x = f2bf(s0); o.y = f2bf(s1); o.z = f2bf(s2); o.w = f2bf(s3);
        *(ushort4*)(Ws + (size_t)n * KK + i) = o;
        if ((tid & 63) == 0) {
            float sb = 0.f;
#pragma unroll
            for (int e = 0; e < 8; ++e) sb += bexp[(g * 8 + e) * 256 + h];
            bs[n] = sb;
        }
    } else {
        int idx = (blk - 512) * 256 + t;      // 0..524287
        const float4* xv = (const float4*)x;
#pragma unroll
        for (int it = 0; it < 4; ++it) {
            const int j = idx + it * 524288;
            const float4 v = xv[j];
            ushort4 o;
            o.x = f2bf(v.x); o.y = f2bf(v.y); o.z = f2bf(v.z); o.w = f2bf(v.w);
            *(ushort4*)(xb + (size_t)j * 4) = o;
        }
    }
}

// ---------------- GEMM: C = A * Bt^T + bias ----------------
// 128x128 tile, BK=64, 4 waves (2x2 of 64x64), 16x16x32 bf16 MFMA.
// LDS layout: row-major 128 x 64, each row's eight 8-elem chunks permuted by
// chunk^(row&7), applied on the GLOBAL source address (glds LDS dest is
// forced to base+lane*16). Fragment reads land 2-way bank-aliased (free).
__global__ __launch_bounds__(256, 3) void gemm_kernel(
    const u16* __restrict__ A, const u16* __restrict__ Bt,
    const float* __restrict__ bias, float* __restrict__ C)
{
    __shared__ __align__(16) u16 sA[128 * BK];
    __shared__ __align__(16) u16 sB[128 * BK];

    const int t = threadIdx.x;
    const int n0 = blockIdx.x * 128;   // x fastest: 16 consecutive blocks share A-tile
    const int m0 = blockIdx.y * 128;

    const int lane = t & 63;
    const int w = t >> 6;
    const int wm = (w & 1) << 6;
    const int wn = (w >> 1) << 6;
    const int lr = lane & 15;
    const int quad = lane >> 4;

    f32x4 acc[4][4] = {};

    // staging: 4 rounds per operand; slot = r*256+t -> row = slot>>3, cs = slot&7
    const int srow = t >> 3;
    const int scs  = t & 7;

    for (int k0 = 0; k0 < KK; k0 += BK) {
#pragma unroll
        for (int r = 0; r < 4; ++r) {
            const int row = srow + r * 32;
            const int gc  = ((scs ^ (row & 7)) << 3);   // swizzled element offset
            gld16(A  + (size_t)(m0 + row) * KK + k0 + gc, sA + (size_t)(r * 256 + t) * 8);
            gld16(Bt + (size_t)(n0 + row) * KK + k0 + gc, sB + (size_t)(r * 256 + t) * 8);
        }
        __syncthreads();

#pragma unroll
        for (int kk = 0; kk < 2; ++kk) {
            bf16x8 af[4], bf[4];
#pragma unroll
            for (int mi = 0; mi < 4; ++mi) {
                const int rr = wm + mi * 16 + lr;
                const int c  = (kk * 4 + quad) ^ (rr & 7);
                af[mi] = *(const bf16x8*)(sA + rr * BK + (c << 3));
            }
#pragma unroll
            for (int ni = 0; ni < 4; ++ni) {
                const int rr = wn + ni * 16 + lr;
                const int c  = (kk * 4 + quad) ^ (rr & 7);
                bf[ni] = *(const bf16x8*)(sB + rr * BK + (c << 3));
            }
#pragma unroll
            for (int mi = 0; mi < 4; ++mi)
#pragma unroll
                for (int ni = 0; ni < 4; ++ni)
                    acc[mi][ni] = __builtin_amdgcn_mfma_f32_16x16x32_bf16(
                        af[mi], bf[ni], acc[mi][ni], 0, 0, 0);
        }
        __syncthreads();
    }

    // epilogue: C/D layout col=lane&15, row=quad*4+reg (m89-verified).
    // NONTEMPORAL stores: C is write-once/never-read -> bypass L2, keep A/B hot.
#pragma unroll
    for (int ni = 0; ni < 4; ++ni) {
        const int col = n0 + wn + ni * 16 + lr;
        const float bv = bias[col];
#pragma unroll
        for (int mi = 0; mi < 4; ++mi) {
            const int row = m0 + wm + mi * 16 + quad * 4;
            float* Cp = C + (size_t)row * NN + col;
#pragma unroll
            for (int r = 0; r < 4; ++r)
                __builtin_nontemporal_store(acc[mi][ni][r] + bv, Cp + (size_t)r * NN);
        }
    }
}

extern "C" void kernel_launch(void* const* d_in, const int* in_sizes, int n_in,
                              void* d_out, int out_size, void* d_ws, size_t ws_size,
                              hipStream_t stream) {
    const float* x    = (const float*)d_in[0];
    // d_in[1] = W_gate, d_in[2] = b_gate: unused (softmax row-sum == 1)
    const float* Wexp = (const float*)d_in[3];
    const float* bexp = (const float*)d_in[4];
    float* out = (float*)d_out;

    u16*   xb = (u16*)d_ws;                                         // 16 MB
    u16*   Ws = (u16*)((char*)d_ws + (size_t)16777216);             // 1 MB
    float* bs = (float*)((char*)d_ws + (size_t)16777216 + 1048576); // 8 KB

    prep_kernel<<<2560, 256, 0, stream>>>(x, Wexp, bexp, xb, Ws, bs);
    dim3 grid(NN / 128, MB / 128);  // (16, 256) — n fastest
    gemm_kernel<<<grid, 256, 0, stream>>>(xb, Ws, bs, out);
}